// Round 1
// baseline (1156.576 us; speedup 1.0000x reference)
//
#include <hip/hip_runtime.h>

#define WAVE 64

__device__ __forceinline__ float wave_reduce_sum(float v) {
#pragma unroll
    for (int off = 32; off > 0; off >>= 1)
        v += __shfl_xor(v, off, 64);
    return v;
}

// ---------------------------------------------------------------------------
// K0 (fused radial MLP): h = silu(LN(ED @ W1 + b1)); w_edge = h @ W2 + b2.
// 4 waves/block, 8 edges/wave (weights register-reused across 8 edges).
// h handed off wave-locally through LDS (no HBM round-trip, one barrier).
// w_edge written interleaved into the after_Dij output region: slot e has
// 1792 floats, w_edge occupies [0,512) (read-then-overwritten by k_main).
// No early return: lanes past E clamp to edge 0 and skip stores, so all
// 256 threads reach the barrier.
// ---------------------------------------------------------------------------
__global__ __launch_bounds__(256) void k_radial(
    const float* __restrict__ ED, const float* __restrict__ W1,
    const float* __restrict__ b1, const float* __restrict__ g1,
    const float* __restrict__ be1, const float* __restrict__ W2,
    const float* __restrict__ b2, float* __restrict__ AD, int E)
{
    int t = threadIdx.x;
    int j = t & 63;
    int w = __builtin_amdgcn_readfirstlane(t >> 6);
    long e0 = (long)blockIdx.x * 32 + (long)w * 8;
    int ne = 0;
    if (e0 < E) ne = (int)((E - e0) < 8 ? (E - e0) : 8);
    long eidx[8];
#pragma unroll
    for (int e = 0; e < 8; ++e) eidx[e] = (e0 < E) ? (e0 + (e < ne ? e : 0)) : 0;

    // ---- stage 1: h = silu(LN(ED @ W1 + b1)) ----
    float h[8];
    float bj = b1[j];
#pragma unroll
    for (int e = 0; e < 8; ++e) h[e] = bj;

    for (int i = 0; i < 128; ++i) {
        float w1v = W1[i * 64 + j];
#pragma unroll
        for (int e = 0; e < 8; ++e)
            h[e] += ED[eidx[e] * 128 + i] * w1v;   // eidx wave-uniform -> s_load
    }

    __shared__ float s_h[4 * 8 * 64];   // [wave][edge][chan], 8 KB
    float gj = g1[j], bj2 = be1[j];
#pragma unroll
    for (int e = 0; e < 8; ++e) {
        float s = wave_reduce_sum(h[e]);
        float q = wave_reduce_sum(h[e] * h[e]);
        float mu = s * (1.f / 64.f);
        float var = q * (1.f / 64.f) - mu * mu;
        float hn = (h[e] - mu) * rsqrtf(var + 1e-5f) * gj + bj2;
        float sv = hn / (1.f + __expf(-hn));  // silu
        s_h[w * 512 + e * 64 + j] = sv;
    }
    __syncthreads();

    // ---- stage 2: w_edge = h @ W2 + b2  (64 x 512) ----
    float acc[8][8];
#pragma unroll
    for (int m = 0; m < 8; ++m) {
        float bv = b2[m * 64 + j];
#pragma unroll
        for (int e = 0; e < 8; ++e) acc[e][m] = bv;
    }

    for (int i = 0; i < 64; ++i) {
        float hv[8];
#pragma unroll
        for (int e = 0; e < 8; ++e) hv[e] = s_h[w * 512 + e * 64 + i];  // broadcast
#pragma unroll
        for (int m = 0; m < 8; ++m) {
            float w2v = W2[i * 512 + m * 64 + j];
#pragma unroll
            for (int e = 0; e < 8; ++e) acc[e][m] += hv[e] * w2v;
        }
    }

#pragma unroll
    for (int e = 0; e < 8; ++e) {
        if (e < ne) {
#pragma unroll
            for (int m = 0; m < 8; ++m)
                AD[eidx[e] * 1792 + m * 64 + j] = acc[e][m];
        }
    }
}

// ---------------------------------------------------------------------------
// K1: per-edge fused: gather*w_edge, wigner rotate -> after_Dij, fij0,
// row means -> fijL, grid roundtrip -> xm2, y = wig^T xm2, alpha logits
// -> ex, atomic den. One block (128 thr) per edge; thread c owns channel c.
// ---------------------------------------------------------------------------
__global__ __launch_bounds__(128) void k_main(
    const float* __restrict__ xsrc, const float* __restrict__ xdst,
    const float* __restrict__ wigner,
    const float* __restrict__ to_grid, const float* __restrict__ from_grid,
    const float* __restrict__ a_g, const float* __restrict__ a_b,
    const float* __restrict__ a_dot,
    const int* __restrict__ esrc, const int* __restrict__ edst,
    float* __restrict__ AD, float* __restrict__ F0, float* __restrict__ FL,
    float* __restrict__ ws_ex, float* __restrict__ ws_xm2,
    float* __restrict__ ws_y, float* __restrict__ ws_den, int E)
{
    long e = blockIdx.x;
    if (e >= E) return;
    int c = threadIdx.x;

    // w_edge for this edge (staged in this edge's own AD slot by k_radial)
    float we[4];
#pragma unroll
    for (int l = 0; l < 4; ++l) we[l] = AD[e * 1792 + l * 128 + c];

    int src = esrc[e], dst = edst[e];
    const float* xb = (c < 64) ? (xsrc + (long)src * 1024 + c)
                               : (xdst + (long)dst * 1024 + (c - 64));

    float xmsg[16];
    // L_INDEX = 0,1,1,1,2,2,2,2,2,3,3,3,3,3,3,3 (compile-time folded)
    xmsg[0]  = xb[0 * 64]  * we[0];
    xmsg[1]  = xb[1 * 64]  * we[1];
    xmsg[2]  = xb[2 * 64]  * we[1];
    xmsg[3]  = xb[3 * 64]  * we[1];
    xmsg[4]  = xb[4 * 64]  * we[2];
    xmsg[5]  = xb[5 * 64]  * we[2];
    xmsg[6]  = xb[6 * 64]  * we[2];
    xmsg[7]  = xb[7 * 64]  * we[2];
    xmsg[8]  = xb[8 * 64]  * we[2];
    xmsg[9]  = xb[9 * 64]  * we[3];
    xmsg[10] = xb[10 * 64] * we[3];
    xmsg[11] = xb[11 * 64] * we[3];
    xmsg[12] = xb[12 * 64] * we[3];
    xmsg[13] = xb[13 * 64] * we[3];
    xmsg[14] = xb[14 * 64] * we[3];
    xmsg[15] = xb[15 * 64] * we[3];

    const int MASKA[14] = {0, 1, 2, 3, 4, 5, 6, 7, 8, 10, 11, 12, 13, 14};
    const float* wigE = wigner + e * 256;  // uniform -> scalar loads
    float xr[14];
#pragma unroll
    for (int m = 0; m < 14; ++m) {
        const float* wr = wigE + MASKA[m] * 16;
        float acc = 0.f;
#pragma unroll
        for (int n = 0; n < 16; ++n) acc += wr[n] * xmsg[n];
        xr[m] = acc;
    }

    // after_Dij + fij0 (overwrites the staged w_edge; same-thread addresses)
#pragma unroll
    for (int m = 0; m < 14; ++m) AD[e * 1792 + m * 128 + c] = xr[m];
    F0[e * 128 + c] = xr[0];

    // row means over 128 channels via LDS transpose (row pad 132: +4 floats,
    // 528B rows keep 16B alignment for float4 reads; 2-way banking = free)
    __shared__ float s_xr[14 * 132];
    __shared__ float s_part[14 * 8];
    __shared__ float s_xm[14];
    __shared__ float s_xm2[14];
    __shared__ float s_g[64];
    __shared__ float s_red[6];

#pragma unroll
    for (int m = 0; m < 14; ++m) s_xr[m * 132 + c] = xr[m];
    __syncthreads();

    if (c < 112) {
        int m = c >> 3, seg = c & 7;
        const float* base = s_xr + m * 132 + seg * 16;
        float s = 0.f;
#pragma unroll
        for (int k = 0; k < 16; ++k) s += base[k];
        s_part[m * 8 + seg] = s;
    }
    __syncthreads();

    if (c < 14) {
        float s = 0.f;
#pragma unroll
        for (int k = 0; k < 8; ++k) s += s_part[c * 8 + k];
        float xmv = s * (1.f / 128.f);
        s_xm[c] = xmv;
        FL[e * 14 + c] = xmv;  // fijL = pre-grid mean
    }
    __syncthreads();

    // grid roundtrip: g = silu(to_grid @ xm); xm2 = from_grid^T @ g
    if (c < 64) {
        float acc = 0.f;
#pragma unroll
        for (int i = 0; i < 14; ++i) acc += to_grid[c * 14 + i] * s_xm[i];
        s_g[c] = acc / (1.f + __expf(-acc));
    }
    __syncthreads();

    // from_grid^T @ g parallelized over 112 lanes (8-term partials), then
    // 14-lane tree reduce — replaces the old 14-lane x 64-iter serial chain.
    if (c < 112) {
        int m = c >> 3, seg = c & 7;
        float acc = 0.f;
#pragma unroll
        for (int k = 0; k < 8; ++k) {
            int p = seg * 8 + k;
            acc += from_grid[p * 14 + m] * s_g[p];
        }
        s_part[m * 8 + seg] = acc;
    }
    __syncthreads();

    if (c < 14) {
        float acc = 0.f;
#pragma unroll
        for (int k = 0; k < 8; ++k) acc += s_part[c * 8 + k];
        s_xm2[c] = acc;
        ws_xm2[e * 14 + c] = acc;
    }
    __syncthreads();

    // y[n] = sum_m wig[MASK[m]][n] * xm2[m]
    if (c < 16) {
        float acc = 0.f;
#pragma unroll
        for (int m = 0; m < 14; ++m) acc += wigE[MASKA[m] * 16 + c] * s_xm2[m];
        ws_y[e * 16 + c] = acc;
    }

    // alpha: smooth_leaky(LN(x0)) . alpha_dot, then ex = exp(alpha)
    float x0 = xr[0];
    float s1 = wave_reduce_sum(x0);
    float s2 = wave_reduce_sum(x0 * x0);
    int wid = c >> 6;
    if ((c & 63) == 0) { s_red[wid * 2] = s1; s_red[wid * 2 + 1] = s2; }
    __syncthreads();
    float su = s_red[0] + s_red[2];
    float sq = s_red[1] + s_red[3];
    float mu = su * (1.f / 128.f);
    float var = sq * (1.f / 128.f) - mu * mu;
    float an = (x0 - mu) * rsqrtf(var + 1e-5f) * a_g[c] + a_b[c];
    float sl = 0.6f * an + 0.4f * an * (2.f / (1.f + __expf(-an)) - 1.f);
    float contrib = sl * a_dot[c];
    float cs = wave_reduce_sum(contrib);
    if ((c & 63) == 0) s_red[4 + wid] = cs;
    __syncthreads();
    if (c == 0) {
        float alpha = s_red[4] + s_red[5];
        // no segment_max needed: |alpha| is O(4), exp cannot overflow, and
        // ex/den is max-shift invariant up to the 1e-16 guard (negligible)
        float ex = __expf(alpha);
        ws_ex[e] = ex;
        atomicAdd(&ws_den[dst], ex);
    }
}

// ---------------------------------------------------------------------------
// K2: normalize + scatter. 16 lanes per edge (lockstep within a wave, so
// aliasing ws_ex->AIJ and ws_xm2->VIJ read-then-overwrite is safe).
// ---------------------------------------------------------------------------
__global__ __launch_bounds__(256) void k_norm_scatter(
    const float* __restrict__ ws_ex, const float* __restrict__ ws_den,
    const float* __restrict__ ws_xm2, const float* __restrict__ ws_y,
    const int* __restrict__ edst,
    float* __restrict__ AIJ, float* __restrict__ VIJ,
    float* __restrict__ ws_node, int E)
{
    long tid = (long)blockIdx.x * 256 + threadIdx.x;
    long e = tid >> 4;
    int n = (int)(tid & 15);
    if (e >= E) return;
    int dst = edst[e];
    float an = ws_ex[e] / (ws_den[dst] + 1e-16f);
    if (n == 0) AIJ[e] = an;
    if (n < 14) VIJ[e * 14 + n] = an * ws_xm2[e * 14 + n];
    atomicAdd(&ws_node[(long)dst * 16 + n], an * ws_y[e * 16 + n]);
}

// ---------------------------------------------------------------------------
// K3: out[b,m,o] = node[b,m] * proj_w[L_INDEX[m]][o] (+ proj_b[o] at m=0)
// ---------------------------------------------------------------------------
__global__ __launch_bounds__(256) void k_proj(
    const float* __restrict__ ws_node, const float* __restrict__ proj_w,
    const float* __restrict__ proj_b, float* __restrict__ OUT, int N)
{
    int b = blockIdx.x;
    if (b >= N) return;
    int t = threadIdx.x;
    __shared__ float s_nd[16];
    if (t < 16) s_nd[t] = ws_node[(long)b * 16 + t];
    __syncthreads();
    int o = t & 63;
    int m0 = t >> 6;
    float pb = proj_b[o];
#pragma unroll
    for (int k = 0; k < 4; ++k) {
        int m = m0 + k * 4;
        int l = (m >= 9) ? 3 : (m >= 4) ? 2 : (m >= 1) ? 1 : 0;
        float v = s_nd[m] * proj_w[l * 64 + o];
        if (m == 0) v += pb;
        OUT[(long)b * 1024 + m * 64 + o] = v;
    }
}

extern "C" void kernel_launch(void* const* d_in, const int* in_sizes, int n_in,
                              void* d_out, int out_size, void* d_ws, size_t ws_size,
                              hipStream_t stream)
{
    (void)n_in; (void)out_size; (void)ws_size;
    const float* xsrc = (const float*)d_in[0];
    const float* xdst = (const float*)d_in[1];
    const float* ED   = (const float*)d_in[2];
    const float* wig  = (const float*)d_in[3];
    const float* tg   = (const float*)d_in[4];
    const float* fg   = (const float*)d_in[5];
    const float* W1   = (const float*)d_in[6];
    const float* b1   = (const float*)d_in[7];
    const float* g1   = (const float*)d_in[8];
    const float* be1  = (const float*)d_in[9];
    const float* W2   = (const float*)d_in[10];
    const float* b2   = (const float*)d_in[11];
    const float* ag   = (const float*)d_in[12];
    const float* ab   = (const float*)d_in[13];
    const float* adot = (const float*)d_in[14];
    const float* pw   = (const float*)d_in[15];
    const float* pb   = (const float*)d_in[16];
    const int* esrc   = (const int*)d_in[17];
    const int* edst   = (const int*)d_in[18];

    int E = in_sizes[17];          // 80000
    int N = in_sizes[0] / 1024;    // 10000

    // output layout (return order, flat):
    float* out = (float*)d_out;
    float* OUT0 = out;                              // (N,16,64)
    float* AD   = OUT0 + (long)N * 1024;            // after_Dij (E,14,128)
    float* F0   = AD + (long)E * 1792;              // fij0 (E,128)
    float* FL   = F0 + (long)E * 128;               // fijL (E,14)
    float* AIJ  = FL + (long)E * 14;                // aij (E)
    float* VIJ  = AIJ + (long)E;                    // vij (E,14)

    // scratch: den[N], node[N*16], y[E*16]  (ex->AIJ, xm2->VIJ aliased)
    float* ws      = (float*)d_ws;
    float* ws_den  = ws;
    float* ws_node = ws + N;
    float* ws_y    = ws + (long)N * 17;
    float* ws_ex   = AIJ;      // K2 reads then overwrites (same wave, lockstep)
    float* ws_xm2  = VIJ;

    hipMemsetAsync(d_ws, 0, sizeof(float) * (size_t)N * 17, stream);

    int nb32 = (E + 31) / 32;
    k_radial<<<nb32, 256, 0, stream>>>(ED, W1, b1, g1, be1, W2, b2, AD, E);
    k_main<<<E, 128, 0, stream>>>(xsrc, xdst, wig, tg, fg, ag, ab, adot,
                                  esrc, edst, AD, F0, FL,
                                  ws_ex, ws_xm2, ws_y, ws_den, E);
    k_norm_scatter<<<(E * 16 + 255) / 256, 256, 0, stream>>>(
        ws_ex, ws_den, ws_xm2, ws_y, edst, AIJ, VIJ, ws_node, E);
    k_proj<<<N, 256, 0, stream>>>(ws_node, pw, pb, OUT0, N);
}